// Round 12
// baseline (182.781 us; speedup 1.0000x reference)
//
#include <hip/hip_runtime.h>
#include <math.h>

#define T_TOK 1024
#define H_DIM 1024
#define NEXP  16
#define I_DIM 512
#define ISH   1024
#define GU_GRID 256
#define DN_GRID 384

typedef __bf16 bf16;
typedef __bf16 bf16x4 __attribute__((ext_vector_type(4)));
typedef __bf16 bf16x8 __attribute__((ext_vector_type(8)));
typedef float  f32x4  __attribute__((ext_vector_type(4)));
typedef unsigned int u32;

#define MFMA(a,b,c) __builtin_amdgcn_mfma_f32_16x16x32_bf16(a,b,c,0,0,0)

__device__ __forceinline__ bf16x8 cvt8(float4 a, float4 b) {
    return (bf16x8){ (bf16)a.x,(bf16)a.y,(bf16)a.z,(bf16)a.w,
                     (bf16)b.x,(bf16)b.y,(bf16)b.z,(bf16)b.w };
}
__device__ __forceinline__ void gload16(const void* g, void* l) {
    __builtin_amdgcn_global_load_lds((const __attribute__((address_space(1))) u32*)g,
                                     (__attribute__((address_space(3))) u32*)l, 16, 0, 0);
}
#define WAITS  { asm volatile("s_waitcnt lgkmcnt(0)" ::: "memory"); \
                 asm volatile("s_waitcnt vmcnt(0)" ::: "memory"); \
                 __builtin_amdgcn_sched_barrier(0); }
#define SBAR   __builtin_amdgcn_s_barrier()

// ---------------- fused cast(x->bf16) + router ----------------
__global__ __launch_bounds__(256) void k_cast_router(const float* __restrict__ x,
        const float* __restrict__ gw, const float* __restrict__ bias,
        bf16* __restrict__ xb, int* __restrict__ tok_e, float* __restrict__ tok_w)
{
    int t = blockIdx.x * 4 + (threadIdx.x >> 6);
    int lane = threadIdx.x & 63;
    const float* xrow = x + (size_t)t * H_DIM + lane * 16;
    bf16* xbrow = xb + (size_t)t * H_DIM + lane * 16;
    float acc[NEXP];
    #pragma unroll
    for (int e = 0; e < NEXP; ++e) acc[e] = 0.f;
    #pragma unroll
    for (int kc = 0; kc < 4; ++kc) {
        float4 xv = *(const float4*)(xrow + kc * 4);
        bf16x4 o = { (bf16)xv.x, (bf16)xv.y, (bf16)xv.z, (bf16)xv.w };
        *(bf16x4*)(xbrow + kc * 4) = o;
        const float* gp = gw + lane * 16 + kc * 4;
        #pragma unroll
        for (int e = 0; e < NEXP; ++e) {
            float4 wv = *(const float4*)(gp + e * H_DIM);
            acc[e] += xv.x * wv.x + xv.y * wv.y + xv.z * wv.z + xv.w * wv.w;
        }
    }
    #pragma unroll
    for (int e = 0; e < NEXP; ++e) {
        float v = acc[e];
        #pragma unroll
        for (int off = 1; off < 64; off <<= 1) v += __shfl_xor(v, off);
        acc[e] = v;
    }
    if (lane == 0) {
        float sc[NEXP], bi[NEXP];
        #pragma unroll
        for (int e = 0; e < NEXP; ++e) {
            sc[e] = 1.f / (1.f + expf(-acc[e]));
            bi[e] = sc[e] + bias[e];
        }
        int i1 = 0; float b1 = bi[0];
        for (int e = 1; e < NEXP; ++e) if (bi[e] > b1) { b1 = bi[e]; i1 = e; }
        int i2 = -1; float b2 = -1e30f;
        for (int e = 0; e < NEXP; ++e) { if (e == i1) continue; if (bi[e] > b2) { b2 = bi[e]; i2 = e; } }
        float w1 = sc[i1], w2 = sc[i2];
        float s = w1 + w2;
        w1 /= s; w2 /= s;
        tok_e[t * 2]     = i1;  tok_e[t * 2 + 1] = i2;
        tok_w[t * 2]     = w1;  tok_w[t * 2 + 1] = w2;
    }
}

// ---------------- cast shared weights fp32 -> bf16 (12 MB -> 6 MB) ----------------
__global__ __launch_bounds__(256) void k_cast_sh(const float* __restrict__ sgu,
        const float* __restrict__ sd, bf16* __restrict__ sgu_b, bf16* __restrict__ sd_b)
{
    size_t i = ((size_t)blockIdx.x * 256 + threadIdx.x) * 8;
    const float* src; bf16* dst;
    if (i < (size_t)2097152) { src = sgu + i; dst = sgu_b + i; }
    else { src = sd + (i - 2097152); dst = sd_b + (i - 2097152); }
    float4 a = *(const float4*)src, b = *(const float4*)(src + 4);
    *(bf16x8*)dst = cvt8(a, b);
}

// ---------------- build: histogram + scan + scatter ----------------
__global__ __launch_bounds__(256) void k_build(const int* __restrict__ tok_e,
        const float* __restrict__ tok_w, int* __restrict__ offs_g,
        int* __restrict__ row_token, float* __restrict__ row_w)
{
    __shared__ int cnt[NEXP], cur[NEXP];
    int tid = threadIdx.x;
    if (tid < NEXP) cnt[tid] = 0;
    __syncthreads();
    for (int p = tid; p < 2 * T_TOK; p += 256) atomicAdd(&cnt[tok_e[p]], 1);
    __syncthreads();
    if (tid == 0) {
        int s = 0;
        for (int e = 0; e < NEXP; ++e) { offs_g[e] = s; cur[e] = s; s += cnt[e]; }
        offs_g[NEXP] = s;
    }
    __syncthreads();
    for (int p = tid; p < 2 * T_TOK; p += 256) {
        int e = tok_e[p];
        int pos = atomicAdd(&cur[e], 1);
        row_token[pos] = p >> 1;
        row_w[pos] = tok_w[p];
    }
}

// ---------------- gate_up + SwiGLU: panel blocks + in-block M loop ----------------
// routed: idx<128 -> (e=idx>>3, nx=idx&7), M-loop over expert tiles, fp32 weights (1x stream)
// shared: idx>=128 -> (nx=(idx-128)>>3, mt=(idx-128)&7), bf16 pre-cast weights
__global__ __launch_bounds__(512) void k_gu(
    const bf16* __restrict__ xb, const float* __restrict__ wgu, const bf16* __restrict__ sgu_b,
    bf16* __restrict__ act, bf16* __restrict__ act2,
    const int* __restrict__ offs, const int* __restrict__ row_token)
{
    __shared__ char A_l[2 * 16384];            // 2 x [128][64] bf16, XOR-swizzled
    __shared__ bf16 Gl[2][64][72];
    __shared__ bf16 Ul[2][64][72];
    __shared__ int  toks[128];

    int bid = blockIdx.x;
    int idx = (bid & 7) * (GU_GRID >> 3) + (bid >> 3);
    bool sh = idx >= 128;
    int e = 0, nx, smt = 0, base = 0, ntile, ldo;
    bf16* dst;
    if (sh) {
        int j = idx - 128; nx = j >> 3; smt = j & 7;
        ntile = 1; ldo = ISH; dst = act2;
    } else {
        e = idx >> 3; nx = idx & 7;
        base = offs[e];
        int cnt = offs[e + 1] - base;
        ntile = (cnt + 127) >> 7;
        if (ntile == 0) return;
        ldo = I_DIM; dst = act;
    }
    int n0 = nx * 64;
    const float *Wg = nullptr, *Wu = nullptr;
    const bf16 *Wgb = nullptr, *Wub = nullptr;
    if (sh) {
        Wgb = sgu_b + (size_t)n0 * H_DIM;
        Wub = sgu_b + (size_t)(ISH + n0) * H_DIM;
    } else {
        const float* W = wgu + (size_t)e * (2 * (size_t)I_DIM * H_DIM);
        Wg = W + (size_t)n0 * H_DIM;
        Wu = W + (size_t)(I_DIM + n0) * H_DIM;
    }

    int tid = threadIdx.x;
    int lane = tid & 63, w = tid >> 6, wm = w >> 1, wn = w & 1;
    int lr = lane & 15, hi = lane >> 4, lk8 = hi * 8;
    int rg = tid >> 3, c8 = (tid & 7) * 8;     // B staging: row 0..63, 8 cols

    for (int tile = 0; tile < ntile; ++tile) {
        int m0 = sh ? smt * 128 : base + tile * 128;
        int mcnt = sh ? 128 : min(128, offs[e + 1] - m0);
        __syncthreads();
        if (tid < 128) toks[tid] = sh ? (m0 + tid) : row_token[m0 + min(tid, mcnt - 1)];
        __syncthreads();

        const bf16* srcA[2]; int offA[2];
        #pragma unroll
        for (int c = 0; c < 2; ++c) {
            int o = (c * 512 + tid) * 16;
            int r = o >> 7;
            int cb = (o & 127) ^ ((r & 7) << 4);
            srcA[c] = xb + (size_t)toks[r] * H_DIM + (cb >> 1);
            offA[c] = o;
        }

        f32x4 aG[2][2], aU[2][2];
        #pragma unroll
        for (int m = 0; m < 2; ++m)
            #pragma unroll
            for (int n = 0; n < 2; ++n) { aG[m][n] = (f32x4){0,0,0,0}; aU[m][n] = (f32x4){0,0,0,0}; }

        // prologue: tile k=0 -> buf 0
        {
            bf16x8 gb, ub; float4 g0, g1, u0, u1;
            if (sh) {
                gb = *(const bf16x8*)(Wgb + (size_t)rg * H_DIM + c8);
                ub = *(const bf16x8*)(Wub + (size_t)rg * H_DIM + c8);
            } else {
                const float* pg = Wg + (size_t)rg * H_DIM + c8;
                const float* pu = Wu + (size_t)rg * H_DIM + c8;
                g0 = *(const float4*)pg; g1 = *(const float4*)(pg + 4);
                u0 = *(const float4*)pu; u1 = *(const float4*)(pu + 4);
            }
            gload16(srcA[0], A_l + offA[0]);
            gload16(srcA[1], A_l + offA[1]);
            if (sh) { *(bf16x8*)&Gl[0][rg][c8] = gb; *(bf16x8*)&Ul[0][rg][c8] = ub; }
            else    { *(bf16x8*)&Gl[0][rg][c8] = cvt8(g0, g1); *(bf16x8*)&Ul[0][rg][c8] = cvt8(u0, u1); }
            WAITS; SBAR;
        }

        for (int t = 0; t < 16; ++t) {
            int c = t & 1;
            bool pf = (t < 15);
            bf16x8 gb, ub; float4 g0, g1, u0, u1;
            if (pf) {
                int kb = (t + 1) * 64;
                if (sh) {
                    gb = *(const bf16x8*)(Wgb + (size_t)rg * H_DIM + kb + c8);
                    ub = *(const bf16x8*)(Wub + (size_t)rg * H_DIM + kb + c8);
                } else {
                    const float* pg = Wg + (size_t)rg * H_DIM + kb + c8;
                    const float* pu = Wu + (size_t)rg * H_DIM + kb + c8;
                    g0 = *(const float4*)pg; g1 = *(const float4*)(pg + 4);
                    u0 = *(const float4*)pu; u1 = *(const float4*)(pu + 4);
                }
                gload16(srcA[0] + kb, A_l + (c ^ 1) * 16384 + offA[0]);
                gload16(srcA[1] + kb, A_l + (c ^ 1) * 16384 + offA[1]);
            }
            const char* Ab = A_l + c * 16384;
            #pragma unroll
            for (int ks = 0; ks < 2; ++ks) {
                bf16x8 fa[2], fg[2], fu[2];
                #pragma unroll
                for (int mf = 0; mf < 2; ++mf) {
                    int r = wm * 32 + mf * 16 + lr;
                    fa[mf] = *(const bf16x8*)(Ab + r * 128 + (((ks * 32 + lk8) * 2) ^ ((r & 7) << 4)));
                }
                #pragma unroll
                for (int nf = 0; nf < 2; ++nf) {
                    int r = wn * 32 + nf * 16 + lr;
                    fg[nf] = *(const bf16x8*)&Gl[c][r][ks * 32 + lk8];
                    fu[nf] = *(const bf16x8*)&Ul[c][r][ks * 32 + lk8];
                }
                #pragma unroll
                for (int mf = 0; mf < 2; ++mf)
                    #pragma unroll
                    for (int nf = 0; nf < 2; ++nf) {
                        aG[mf][nf] = MFMA(fa[mf], fg[nf], aG[mf][nf]);
                        aU[mf][nf] = MFMA(fa[mf], fu[nf], aU[mf][nf]);
                    }
            }
            if (pf) {
                if (sh) { *(bf16x8*)&Gl[c ^ 1][rg][c8] = gb; *(bf16x8*)&Ul[c ^ 1][rg][c8] = ub; }
                else    { *(bf16x8*)&Gl[c ^ 1][rg][c8] = cvt8(g0, g1); *(bf16x8*)&Ul[c ^ 1][rg][c8] = cvt8(u0, u1); }
                WAITS; SBAR;
            }
        }

        #pragma unroll
        for (int mf = 0; mf < 2; ++mf) {
            #pragma unroll
            for (int j = 0; j < 4; ++j) {
                int rl = wm * 32 + mf * 16 + hi * 4 + j;
                if (rl < mcnt) {
                    #pragma unroll
                    for (int nf = 0; nf < 2; ++nf) {
                        float g = aG[mf][nf][j], u = aU[mf][nf][j];
                        float v = (g / (1.f + __expf(-g))) * u;
                        dst[(size_t)(m0 + rl) * ldo + n0 + wn * 32 + nf * 16 + lr] = (bf16)v;
                    }
                }
            }
        }
    }
}

// ---------------- down proj: panel blocks + in-block M loop, atomic out ----------------
// routed: idx<256 -> (e=idx>>4, nx=idx&15), K=512; shared: (nx,mt), K=1024, bf16 weights
__global__ __launch_bounds__(512) void k_dn(
    const bf16* __restrict__ act, const bf16* __restrict__ act2,
    const float* __restrict__ wd, const bf16* __restrict__ sd_b, float* __restrict__ out,
    const int* __restrict__ offs, const int* __restrict__ row_token, const float* __restrict__ row_w)
{
    __shared__ char A_l[2 * 16384];
    __shared__ bf16 Bl[2][64][72];

    int bid = blockIdx.x;
    int idx = (bid & 7) * (DN_GRID >> 3) + (bid >> 3);
    bool sh = idx >= 256;
    int e = 0, nx, smt = 0, base = 0, ntile, lda, ldw, nt;
    const bf16* A;
    if (sh) {
        int j = idx - 256; nx = j >> 3; smt = j & 7;
        ntile = 1; A = act2; lda = ISH; ldw = ISH; nt = 16;
    } else {
        e = idx >> 4; nx = idx & 15;
        base = offs[e];
        int cnt = offs[e + 1] - base;
        ntile = (cnt + 127) >> 7;
        if (ntile == 0) return;
        A = act; lda = I_DIM; ldw = I_DIM; nt = 8;
    }
    int n0 = nx * 64;
    const float* Wf = sh ? nullptr : wd + (size_t)e * H_DIM * I_DIM + (size_t)n0 * I_DIM;
    const bf16*  Wb = sh ? sd_b + (size_t)n0 * ISH : nullptr;

    int tid = threadIdx.x;
    int lane = tid & 63, w = tid >> 6, wm = w >> 1, wn = w & 1;
    int lr = lane & 15, hi = lane >> 4, lk8 = hi * 8;
    int rg = tid >> 3, c8 = (tid & 7) * 8;

    for (int tile = 0; tile < ntile; ++tile) {
        int m0 = sh ? smt * 128 : base + tile * 128;
        int mcnt = sh ? 128 : min(128, offs[e + 1] - m0);
        __syncthreads();

        const bf16* srcA[2]; int offA[2];
        #pragma unroll
        for (int c = 0; c < 2; ++c) {
            int o = (c * 512 + tid) * 16;
            int r = o >> 7;
            int cb = (o & 127) ^ ((r & 7) << 4);
            srcA[c] = A + (size_t)(m0 + min(r, mcnt - 1)) * lda + (cb >> 1);
            offA[c] = o;
        }

        f32x4 acc[2][2];
        #pragma unroll
        for (int m = 0; m < 2; ++m)
            #pragma unroll
            for (int n = 0; n < 2; ++n) acc[m][n] = (f32x4){0,0,0,0};

        {
            bf16x8 bb; float4 b0, b1;
            if (sh) bb = *(const bf16x8*)(Wb + (size_t)rg * ldw + c8);
            else {
                const float* pb = Wf + (size_t)rg * ldw + c8;
                b0 = *(const float4*)pb; b1 = *(const float4*)(pb + 4);
            }
            gload16(srcA[0], A_l + offA[0]);
            gload16(srcA[1], A_l + offA[1]);
            if (sh) *(bf16x8*)&Bl[0][rg][c8] = bb;
            else    *(bf16x8*)&Bl[0][rg][c8] = cvt8(b0, b1);
            WAITS; SBAR;
        }

        for (int t = 0; t < nt; ++t) {
            int c = t & 1;
            bool pf = (t < nt - 1);
            bf16x8 bb; float4 b0, b1;
            if (pf) {
                int kb = (t + 1) * 64;
                if (sh) bb = *(const bf16x8*)(Wb + (size_t)rg * ldw + kb + c8);
                else {
                    const float* pb = Wf + (size_t)rg * ldw + kb + c8;
                    b0 = *(const float4*)pb; b1 = *(const float4*)(pb + 4);
                }
                gload16(srcA[0] + kb, A_l + (c ^ 1) * 16384 + offA[0]);
                gload16(srcA[1] + kb, A_l + (c ^ 1) * 16384 + offA[1]);
            }
            const char* Ab = A_l + c * 16384;
            #pragma unroll
            for (int ks = 0; ks < 2; ++ks) {
                bf16x8 fa[2], fb[2];
                #pragma unroll
                for (int mf = 0; mf < 2; ++mf) {
                    int r = wm * 32 + mf * 16 + lr;
                    fa[mf] = *(const bf16x8*)(Ab + r * 128 + (((ks * 32 + lk8) * 2) ^ ((r & 7) << 4)));
                }
                #pragma unroll
                for (int nf = 0; nf < 2; ++nf) {
                    int r = wn * 32 + nf * 16 + lr;
                    fb[nf] = *(const bf16x8*)&Bl[c][r][ks * 32 + lk8];
                }
                #pragma unroll
                for (int mf = 0; mf < 2; ++mf)
                    #pragma unroll
                    for (int nf = 0; nf < 2; ++nf)
                        acc[mf][nf] = MFMA(fa[mf], fb[nf], acc[mf][nf]);
            }
            if (pf) {
                if (sh) *(bf16x8*)&Bl[c ^ 1][rg][c8] = bb;
                else    *(bf16x8*)&Bl[c ^ 1][rg][c8] = cvt8(b0, b1);
                WAITS; SBAR;
            }
        }

        #pragma unroll
        for (int mf = 0; mf < 2; ++mf) {
            #pragma unroll
            for (int j = 0; j < 4; ++j) {
                int rl = wm * 32 + mf * 16 + hi * 4 + j;
                if (rl < mcnt) {
                    if (sh) {
                        #pragma unroll
                        for (int nf = 0; nf < 2; ++nf)
                            atomicAdd(&out[(size_t)(m0 + rl) * H_DIM + n0 + wn * 32 + nf * 16 + lr],
                                      acc[mf][nf][j]);
                    } else {
                        int tk = row_token[m0 + rl];
                        float wt = row_w[m0 + rl];
                        #pragma unroll
                        for (int nf = 0; nf < 2; ++nf)
                            atomicAdd(&out[(size_t)tk * H_DIM + n0 + wn * 32 + nf * 16 + lr],
                                      wt * acc[mf][nf][j]);
                    }
                }
            }
        }
    }
}

extern "C" void kernel_launch(void* const* d_in, const int* in_sizes, int n_in,
                              void* d_out, int out_size, void* d_ws, size_t ws_size,
                              hipStream_t stream)
{
    (void)in_sizes; (void)n_in; (void)out_size; (void)ws_size;
    const float* x    = (const float*)d_in[0];
    const float* gw   = (const float*)d_in[1];
    const float* bias = (const float*)d_in[2];
    const float* wgu  = (const float*)d_in[3];
    const float* wd   = (const float*)d_in[4];
    const float* sgu  = (const float*)d_in[5];
    const float* sd   = (const float*)d_in[6];
    float* out = (float*)d_out;

    char* ws = (char*)d_ws;
    int*   offs_g    = (int*)(ws);
    int*   tok_e     = (int*)(ws + 4096);
    float* tok_w     = (float*)(ws + 16384);
    int*   row_token = (int*)(ws + 32768);
    float* row_w     = (float*)(ws + 49152);
    bf16*  xb        = (bf16*)(ws + 65536);                 // 2 MB
    bf16*  act       = (bf16*)(ws + 65536 + (1 << 21));     // 2 MB
    bf16*  act2      = (bf16*)(ws + 65536 + (2 << 21));     // 2 MB
    bf16*  sgu_b     = (bf16*)(ws + 65536 + (3 << 21));     // 4 MB
    bf16*  sd_b      = (bf16*)(ws + 65536 + (5 << 21));     // 2 MB

    hipMemsetAsync(out, 0, (size_t)T_TOK * H_DIM * sizeof(float), stream);
    k_cast_sh<<<1536, 256, 0, stream>>>(sgu, sd, sgu_b, sd_b);
    k_cast_router<<<T_TOK / 4, 256, 0, stream>>>(x, gw, bias, xb, tok_e, tok_w);
    k_build<<<1, 256, 0, stream>>>(tok_e, tok_w, offs_g, row_token, row_w);
    k_gu<<<GU_GRID, 512, 0, stream>>>(xb, wgu, sgu_b, act, act2, offs_g, row_token);
    k_dn<<<DN_GRID, 512, 0, stream>>>(act, act2, wd, sd_b, out, offs_g, row_token, row_w);
}